// Round 13
// baseline (133.031 us; speedup 1.0000x reference)
//
#include <hip/hip_runtime.h>
#include <hip/hip_bf16.h>

#define PI_D 3.14159265358979323846
#define L_TOTAL 2097152
#define NFRAMES 4105      // 1 + L/511
#define NBLK    4108      // hop-blocks b: frames t use blocks t..t+3 + 2 samples of t+4
#define MROWS_P 8216      // 2*NBLK (x/y interleaved)
#define MPAD    8320      // 65 * 128
#define KP      512       // 511 padded
#define NDIM    2048      // 1024 bins * (Re,Im)
#define PSTRIDE 8224      // Pt row stride (>= MROWS_P + 8 slack, 16B aligned)

#define COMBINE_BLOCKS 4352   // 256 f-groups x 17 frame-tiles
#define INVW_BLOCKS 512

// Permuted ("tile-fragment") global layout for Ap and Bp, 16B chunks of 8 bf16:
//   chunk16B(row, kc) = (row>>4)*1024 + kc*16 + (row&15),  kc = k/8 in [0,64)
// GEMM staging reads contiguous 1KB per wave AND LDS lands in MFMA fragment
// order (ds_read_b128 conflict-free; verified rounds 2-12).

// prep branch order: LONGEST-latency bodies first so they overlap the rest
#define BURG_BLOCKS   512
#define FRAMES_BLOCKS 2080   // 520 row-blocks x 4 kc-groups
#define BASIS_BLOCKS  512    // 2048*64/256
#define SARR_BLOCKS   17     // 4352 S entries (also zeroes accumulators)
#define PREP_BLOCKS   (BURG_BLOCKS + FRAMES_BLOCKS + BASIS_BLOCKS + SARR_BLOCKS)

typedef __attribute__((ext_vector_type(8))) short short8;
typedef __attribute__((ext_vector_type(4))) short short4v;
typedef __attribute__((ext_vector_type(4))) float floatx4;
typedef float floatx4u __attribute__((ext_vector_type(4), aligned(4)));   // 4B-aligned vec load

typedef __attribute__((address_space(1))) void gvoid_as1;
typedef __attribute__((address_space(3))) void lvoid_as3;

__device__ __forceinline__ void gld_lds16(const void* g, void* l) {
    __builtin_amdgcn_global_load_lds((gvoid_as1*)g, (lvoid_as3*)l, 16, 0, 0);
}

__device__ __forceinline__ float b2f(short v) {
    unsigned int u = ((unsigned int)(unsigned short)v) << 16;
    return __uint_as_float(u);
}

__device__ __forceinline__ float xorall(float v) {
    v += __shfl_xor(v, 1, 64);
    v += __shfl_xor(v, 2, 64);
    v += __shfl_xor(v, 4, 64);
    v += __shfl_xor(v, 8, 64);
    v += __shfl_xor(v, 16, 64);
    v += __shfl_xor(v, 32, 64);
    return v;
}

__device__ __forceinline__ float wave_reduce(float v) {
    v += __shfl_down(v, 32, 64);
    v += __shfl_down(v, 16, 64);
    v += __shfl_down(v, 8, 64);
    v += __shfl_down(v, 4, 64);
    v += __shfl_down(v, 2, 64);
    v += __shfl_down(v, 1, 64);
    return v;
}

// ---------------- frames branch: build Ap (bf16, permuted chunk layout) ----------------
// Ap[row=2b+s][n] = xp_s[511b + n], n<511 (col 511 = 0).
// Lane map: 16-lane group = 16 consecutive kc of ONE row -> contiguous 512B reads.
__device__ __forceinline__ void frames_body(int bid, int tid,
                                            const float* __restrict__ x,
                                            const float* __restrict__ y,
                                            __hip_bfloat16* __restrict__ A) {
    const int rb = bid >> 2;
    const int kc = (bid & 3) * 16 + (tid & 15);
    const int rowIn = tid >> 4;
    const int row = rb * 16 + rowIn;
    const int ci = rb * 1024 + kc * 16 + rowIn;      // permuted chunk index
    __hip_bfloat16 tmp[8];
    if (row < MROWS_P) {
        const int b = row >> 1;
        const float* src = (row & 1) ? y : x;
        const int p0 = b * 511 + kc * 8 - 1023;      // xp index of element 0
        if (kc < 63 && p0 >= 0 && p0 + 8 <= L_TOTAL) {
            // interior fast path: two vectorized loads (4B-aligned ok)
            floatx4u v0 = *(const floatx4u*)(src + p0);
            floatx4u v1 = *(const floatx4u*)(src + p0 + 4);
#pragma unroll
            for (int e = 0; e < 4; e++) tmp[e] = __float2bfloat16(v0[e]);
#pragma unroll
            for (int e = 0; e < 4; e++) tmp[4 + e] = __float2bfloat16(v1[e]);
        } else {
#pragma unroll
            for (int e = 0; e < 8; e++) {
                const int n = kc * 8 + e;
                float v = 0.f;
                if (n < 511) {
                    int p = p0 + e;
                    if (p < 0) p = -p;
                    else if (p >= L_TOTAL) p = 2 * L_TOTAL - 2 - p;
                    v = src[p];
                }
                tmp[e] = __float2bfloat16(v);
            }
        }
    } else {
#pragma unroll
        for (int e = 0; e < 8; e++) tmp[e] = __float2bfloat16(0.f);
    }
    *(short8*)((char*)A + (size_t)ci * 16) = *(short8*)tmp;
}

// ---------------- basis branch: Bp (bf16, permuted chunk layout) ----------------
// rotation recurrence: sincos at n0 and step, then 7 complex rotations.
__device__ __forceinline__ void basis_body(int bid, int tid,
                                           __hip_bfloat16* __restrict__ Bt) {
    const int ci = bid * 256 + tid;
    const int rb = ci >> 10;
    const int kc = (ci >> 4) & 63;
    const int rowIn = ci & 15;
    const int row = rb * 16 + rowIn;
    const int f = row >> 1;
    const bool isSin = row & 1;
    const int n0 = kc * 8;
    const int m0 = (f * n0) % 2046;          // exact angle mod 2pi at n0
    float s, c, ss, cs;
    __sincosf((float)m0 * (float)(PI_D / 1023.0), &s, &c);
    __sincosf((float)f * (float)(PI_D / 1023.0), &ss, &cs);
    __hip_bfloat16 tmp[8];
#pragma unroll
    for (int e = 0; e < 8; e++) {
        const int n = n0 + e;
        float v = isSin ? -s : c;
        if (n >= 511) v = 0.f;
        tmp[e] = __float2bfloat16(v);
        float c2 = c * cs - s * ss;          // angle += f*pi/1023
        float s2 = s * cs + c * ss;
        c = c2; s = s2;
    }
    *(short8*)((char*)Bt + (size_t)ci * 16) = *(short8*)tmp;
}

// ---------------- S branch: tail-sample table + accumulator zeroing ----------------
__device__ __forceinline__ void sarr_body(int bid, int tid,
                                          const float* __restrict__ x,
                                          const float* __restrict__ y,
                                          float4* __restrict__ S,
                                          float* __restrict__ wsf) {
    if (bid < 8) wsf[bid * 256 + tid] = 0.f;   // zero mse_sum + invW
    const int b = bid * 256 + tid;          // 0..4351
    int p0 = 511 * b - 1023;
    int p1 = p0 + 1;
    int m0 = (p0 < 0) ? -p0 : ((p0 >= L_TOTAL) ? 2 * L_TOTAL - 2 - p0 : p0);
    int m1 = (p1 < 0) ? -p1 : ((p1 >= L_TOTAL) ? 2 * L_TOTAL - 2 - p1 : p1);
    S[b] = make_float4(x[m0], x[m1], y[m0], y[m1]);
}

// ---------------- burg branch: one WAVE per 1024-sample audio block ----------------
__device__ __forceinline__ void burg_body(int bid, int tid,
                                          const float* __restrict__ y,
                                          float* __restrict__ ar_out) {
    const int lane = tid & 63;
    const int wid = tid >> 6;
    const int blk = bid * 4 + wid;
    const float4* yb4 = (const float4*)(y + (size_t)blk * 1024) + lane * 4;

    float t[16];
#pragma unroll
    for (int q = 0; q < 4; q++) {
        float4 v = yb4[q];
        t[q * 4 + 0] = v.x; t[q * 4 + 1] = v.y;
        t[q * 4 + 2] = v.z; t[q * 4 + 3] = v.w;
    }
    float b[16], f[16];
#pragma unroll
    for (int r = 0; r < 16; r++) b[r] = t[r];
#pragma unroll
    for (int r = 0; r < 15; r++) f[r] = t[r + 1];
    {
        float nb = __shfl_down(t[0], 1, 64);
        f[15] = (lane == 63) ? 0.f : nb;
        if (lane == 63) b[15] = 0.f;
    }

    float den = 0.f;
#pragma unroll
    for (int r = 0; r < 16; r++) den += f[r] * f[r] + b[r] * b[r];
    den = xorall(den);

    float ar_s[13];
    ar_s[0] = 1.f;
#pragma unroll
    for (int j = 1; j < 13; j++) ar_s[j] = 0.f;

#pragma unroll
    for (int i = 0; i < 12; i++) {
        float num = 0.f;
#pragma unroll
        for (int r = 0; r < 16; r++) num += f[r] * b[r];
        num = xorall(num);
        const float k = -2.f * num / den;

        float fu[16], bu[16];
#pragma unroll
        for (int r = 0; r < 16; r++) {
            fu[r] = f[r] + k * b[r];
            bu[r] = b[r] + k * f[r];
        }
        const float f0 = __shfl(fu[0], 0, 64);
        const int pos = 1022 - i;
        const int L = pos >> 4, S = pos & 15;
        const float blast = __shfl(bu[S], L, 64);

        den = (1.f - k * k) * den - blast * blast - f0 * f0;

        float nf = __shfl_down(fu[0], 1, 64);
#pragma unroll
        for (int r = 0; r < 15; r++) f[r] = fu[r + 1];
        f[15] = (lane == 63) ? 0.f : nf;
#pragma unroll
        for (int r = 0; r < 16; r++) b[r] = bu[r];
        if (lane == L) b[S] = 0.f;

        float tmp[13];
#pragma unroll
        for (int js = 1; js <= i + 1; js++) tmp[js] = ar_s[js] + k * ar_s[i + 1 - js];
#pragma unroll
        for (int js = 1; js <= i + 1; js++) ar_s[js] = tmp[js];
    }

#pragma unroll
    for (int j = 0; j < 12; j++)
        if (lane == j) ar_out[(size_t)blk * 12 + j] = ar_s[j];
}

// ---------------- fused prep: burg FIRST (longest-latency), then frames/basis/S -----
__global__ __launch_bounds__(256) void prep_kernel(const float* __restrict__ x,
                                                   const float* __restrict__ y,
                                                   __hip_bfloat16* __restrict__ A,
                                                   __hip_bfloat16* __restrict__ Bt,
                                                   float4* __restrict__ S,
                                                   float* __restrict__ ar,
                                                   float* __restrict__ wsf) {
    const int bid = blockIdx.x;
    const int tid = threadIdx.x;
    if (bid < BURG_BLOCKS) {
        burg_body(bid, tid, y, ar);
    } else if (bid < BURG_BLOCKS + FRAMES_BLOCKS) {
        frames_body(bid - BURG_BLOCKS, tid, x, y, A);
    } else if (bid < BURG_BLOCKS + FRAMES_BLOCKS + BASIS_BLOCKS) {
        basis_body(bid - BURG_BLOCKS - FRAMES_BLOCKS, tid, Bt);
    } else {
        sarr_body(bid - BURG_BLOCKS - FRAMES_BLOCKS - BASIS_BLOCKS, tid, x, y, S, wsf);
    }
}

// ---------------- P-GEMM (8 waves / 512 threads per 128x128 tile) ----------------
// Each wave: 32x64 sub-tile, acc 2x4 (32 AGPR). __launch_bounds__(512,6) targets
// 3 blocks/CU = 24 waves/CU (reg budget 512/6=85; est use ~82) to hide the
// vmcnt(0)+barrier drain. Staging: 1 A-chunk + 1 B-chunk per thread per K-iter,
// contiguous 1KB per wave, fragment-ordered LDS (0 conflicts).
__global__ __launch_bounds__(512, 6) void gemm_p_kernel(
    const __hip_bfloat16* __restrict__ A, const __hip_bfloat16* __restrict__ Bt,
    __hip_bfloat16* __restrict__ Pt) {
    __shared__ __align__(16) __hip_bfloat16 Al[128 * 32];
    __shared__ __align__(16) __hip_bfloat16 Bl[128 * 32];

    const int tid = threadIdx.x;        // 0..511
    const int lane = tid & 63;
    const int w = tid >> 6;             // 0..7
    const int wm = w >> 1;              // 0..3: 32-row slab
    const int wn = w & 1;               // 0..1: 64-col slab
    const int q = lane >> 4, l15 = lane & 15;
    const int tileN = blockIdx.x * 128;
    const int tileM = blockIdx.y * 128;

    floatx4 acc[2][4];
#pragma unroll
    for (int i = 0; i < 2; i++)
#pragma unroll
        for (int j = 0; j < 4; j++) acc[i][j] = (floatx4){0.f, 0.f, 0.f, 0.f};

    const int gg = tid >> 6;            // row-block 0..7
    const int inner = tid & 63;
    const char* pA = (const char*)A + ((((size_t)(tileM >> 4) + gg) << 10) + inner) * 16;
    const char* pB = (const char*)Bt + ((((size_t)(tileN >> 4) + gg) << 10) + inner) * 16;
    char* AlB = (char*)Al;
    char* BlB = (char*)Bl;

    for (int it = 0; it < KP / 32; it++) {
        gld_lds16(pA, AlB + tid * 16);
        gld_lds16(pB, BlB + tid * 16);
        pA += 1024; pB += 1024;        // 64 chunks per row-block per K-step of 32
        __syncthreads();

        short8 af[2], bf[4];
#pragma unroll
        for (int sm = 0; sm < 2; sm++)
            af[sm] = *(const short8*)(AlB + (((wm * 2 + sm) * 64 + lane) * 16));
#pragma unroll
        for (int sn = 0; sn < 4; sn++)
            bf[sn] = *(const short8*)(BlB + (((wn * 4 + sn) * 64 + lane) * 16));
#pragma unroll
        for (int sm = 0; sm < 2; sm++)
#pragma unroll
            for (int sn = 0; sn < 4; sn++)
                acc[sm][sn] = __builtin_amdgcn_mfma_f32_16x16x32_bf16(
                    af[sm], bf[sn], acc[sm][sn], 0, 0, 0);
        __syncthreads();
    }

    // epilogue: C/D col=lane&15 (N), row=quad*4+reg (M). Write Pt[n][m] bf16.
#pragma unroll
    for (int sm = 0; sm < 2; sm++) {
        const int rowBase = tileM + wm * 32 + sm * 16 + q * 4;
        if (rowBase >= MROWS_P) continue;      // pad rows
#pragma unroll
        for (int sn = 0; sn < 4; sn++) {
            const int colG = tileN + wn * 64 + sn * 16 + l15;
            short4v pk;
#pragma unroll
            for (int r = 0; r < 4; r++) {
                __hip_bfloat16 h = __float2bfloat16(acc[sm][sn][r]);
                pk[r] = *(short*)&h;
            }
            *(short4v*)((char*)Pt + ((size_t)colG * PSTRIDE + rowBase) * 2) = pk;
        }
    }
}

// ---------------- combine body: X_t[f] = sum_h W_h P_{t+h}[f] + tail; mse ----------
__device__ __forceinline__ void combine_body(int bx, int ty, int tid,
                                             const __hip_bfloat16* __restrict__ Pt,
                                             const float4* __restrict__ S,
                                             float* __restrict__ mse_sum) {
    const int lane = tid & 63;
    const int wid = tid >> 6;
    const int f = bx * 4 + wid;              // 0..1023

    // twiddles: W_h = e^{-2pi i f*511h/2046}; tails at offsets 2044, 2045
    float wc[4], ws[4];
    wc[0] = 1.f; ws[0] = 0.f;
#pragma unroll
    for (int h = 1; h < 4; h++) {
        int m = (511 * h * f) % 2046;
        float s, c;
        __sincosf((float)m * (float)(PI_D / 1023.0), &s, &c);
        wc[h] = c; ws[h] = -s;
    }
    float wtc0, wts0, wtc1, wts1;
    {
        int m = (2044 * f) % 2046;
        float s, c;
        __sincosf((float)m * (float)(PI_D / 1023.0), &s, &c);
        wtc0 = c; wts0 = -s;
        m = (2045 * f) % 2046;
        __sincosf((float)m * (float)(PI_D / 1023.0), &s, &c);
        wtc1 = c; wts1 = -s;
    }

    const __hip_bfloat16* rowRe = Pt + (size_t)(2 * f) * PSTRIDE;
    const __hip_bfloat16* rowIm = rowRe + PSTRIDE;

    float acc = 0.f;
    const int tt0 = ty * 256 + 4 * lane;
    if (tt0 < NFRAMES) {
        short8 re0 = *(const short8*)(rowRe + 2 * tt0);
        short8 re1 = *(const short8*)(rowRe + 2 * tt0 + 8);
        short8 im0 = *(const short8*)(rowIm + 2 * tt0);
        short8 im1 = *(const short8*)(rowIm + 2 * tt0 + 8);
        float4 sT[4];
#pragma unroll
        for (int d = 0; d < 4; d++) sT[d] = S[tt0 + 4 + d];   // contiguous across wave
        float vr[16], vi[16];
#pragma unroll
        for (int j = 0; j < 8; j++) {
            vr[j] = b2f(re0[j]); vr[j + 8] = b2f(re1[j]);
            vi[j] = b2f(im0[j]); vi[j + 8] = b2f(im1[j]);
        }
#pragma unroll
        for (int d = 0; d < 4; d++) {
            const int tt = tt0 + d;
            if (tt >= NFRAMES) break;
            float xr = 0.f, xi = 0.f, yr = 0.f, yi = 0.f;
#pragma unroll
            for (int h = 0; h < 4; h++) {
                const int qx = 2 * d + 2 * h;
                xr += wc[h] * vr[qx] - ws[h] * vi[qx];
                xi += wc[h] * vi[qx] + ws[h] * vr[qx];
                const int qy = qx + 1;
                yr += wc[h] * vr[qy] - ws[h] * vi[qy];
                yi += wc[h] * vi[qy] + ws[h] * vr[qy];
            }
            const float4 sd = sT[d];
            xr += wtc0 * sd.x + wtc1 * sd.y;
            xi += wts0 * sd.x + wts1 * sd.y;
            yr += wtc0 * sd.z + wtc1 * sd.w;
            yi += wts0 * sd.z + wts1 * sd.w;
            float dm = sqrtf(xr * xr + xi * xi) - sqrtf(yr * yr + yi * yi);
            acc += dm * dm;
        }
    }
    acc = xorall(acc);
    if (lane == 0) atomicAdd(&mse_sum[f], acc);
}

// ---------------- invw body: invW[f] += sum_{b in 16-group, kk} |den|/|num| --------
__device__ __forceinline__ void invw_body(int bid, int tid,
                                          const float* __restrict__ ar,
                                          float* __restrict__ invW) {
    __shared__ float sar[16][12];
    const int f = (bid & 3) * 256 + tid;
    const int b0 = (bid >> 2) * 16;
    if (tid < 16 * 12) ((float*)sar)[tid] = ar[(size_t)b0 * 12 + tid];
    __syncthreads();

    const float omega = (float)(PI_D / 1024.0) * (float)f;
    float sw, cw;
    __sincosf(omega, &sw, &cw);

    float acc = 0.f;
#pragma unroll 4
    for (int bb = 0; bb < 16; bb++) {
        float a0 = sar[bb][0];
        float nr = a0, ni = 0.f, dr = a0, di = 0.f;
        float er = 1.f, ei = 0.f;
        float g1p = 1.f, g2p = 1.f;
#pragma unroll
        for (int j = 1; j < 12; j++) {
            float er2 = er * cw + ei * sw;
            float ei2 = ei * cw - er * sw;
            er = er2; ei = ei2;
            g1p *= 0.92f; g2p *= 0.6f;
            float aj = sar[bb][j];
            float a1 = aj * g1p, a2 = aj * g2p;
            nr += a2 * er; ni += a2 * ei;
            dr += a1 * er; di += a1 * ei;
            float D = dr * dr + di * di;
            float Nn = nr * nr + ni * ni;
            acc += D * __builtin_amdgcn_rsqf(D * Nn);
        }
    }
    atomicAdd(&invW[f], acc);
}

// ---------------- fused invW (FIRST, long-latency) + combine dispatch ----------------
__global__ __launch_bounds__(256) void combine_invw_kernel(
    const __hip_bfloat16* __restrict__ Pt,
    const float4* __restrict__ S,
    float* __restrict__ mse_sum,
    const float* __restrict__ ar,
    float* __restrict__ invW) {
    const int bid = blockIdx.x;
    const int tid = threadIdx.x;
    if (bid < INVW_BLOCKS) {
        invw_body(bid, tid, ar, invW);
    } else {
        const int cb = bid - INVW_BLOCKS;
        combine_body(cb & 255, cb >> 8, tid, Pt, S, mse_sum);
    }
}

// ---------------- final: out = sum_f mse_sum[f]*invW[f] / (4105*22528*1024) ----------------
__global__ void final_kernel(const float* __restrict__ mse_sum,
                             const float* __restrict__ invW,
                             float* __restrict__ out) {
    __shared__ float red[4];
    const int tid = threadIdx.x;
    float lo = 0.f;
    for (int f = tid; f < 1024; f += 256) lo += mse_sum[f] * invW[f];
    lo = wave_reduce(lo);
    if ((tid & 63) == 0) red[tid >> 6] = lo;
    __syncthreads();
    if (tid == 0) {
        float tot = red[0] + red[1] + red[2] + red[3];
        out[0] = tot * (float)(1.0 / (4105.0 * 22528.0 * 1024.0));
    }
}

extern "C" void kernel_launch(void* const* d_in, const int* in_sizes, int n_in,
                              void* d_out, int out_size, void* d_ws, size_t ws_size,
                              hipStream_t stream) {
    const float* x = (const float*)d_in[0];
    const float* y = (const float*)d_in[1];
    float* out = (float*)d_out;

    float* wsf = (float*)d_ws;
    float* mse_sum = wsf;                    // [0,1024) floats
    float* invW = wsf + 1024;                // [1024,2048)
    float* ar = wsf + 2080;                  // 2048*12 floats -> ends byte 106624
    float4* S = (float4*)((char*)d_ws + 131072);                     // 4352*16 = 69,632 B
    __hip_bfloat16* Ap = (__hip_bfloat16*)((char*)d_ws + 262144);    // 8320*512*2 = 8,519,680 B
    __hip_bfloat16* Bp = (__hip_bfloat16*)((char*)d_ws + 8781824);   // 2048*512*2 = 2,097,152 B
    __hip_bfloat16* Pt = (__hip_bfloat16*)((char*)d_ws + 10878976);  // 2048*8224*2 = 33,685,504 B

    prep_kernel<<<PREP_BLOCKS, 256, 0, stream>>>(x, y, Ap, Bp, S, ar, wsf);
    gemm_p_kernel<<<dim3(NDIM / 128, MPAD / 128), 512, 0, stream>>>(Ap, Bp, Pt);
    combine_invw_kernel<<<INVW_BLOCKS + COMBINE_BLOCKS, 256, 0, stream>>>(Pt, S, mse_sum, ar, invW);
    final_kernel<<<1, 256, 0, stream>>>(mse_sum, invW, out);
}

// Round 14
// 127.226 us; speedup vs baseline: 1.0456x; 1.0456x over previous
//
#include <hip/hip_runtime.h>
#include <hip/hip_bf16.h>

#define PI_D 3.14159265358979323846
#define L_TOTAL 2097152
#define NFRAMES 4105      // 1 + L/511
#define NBLK    4108      // hop-blocks b: frames t use blocks t..t+3 + 2 samples of t+4
#define MROWS_P 8216      // 2*NBLK (x/y interleaved)
#define MPAD    8320      // 65 * 128
#define KP      512       // 511 padded
#define NDIM    2048      // 1024 bins * (Re,Im)
#define PSTRIDE 8224      // Pt row stride (>= MROWS_P + 8 slack, 16B aligned)

#define COMBINE_BLOCKS 4352   // 256 f-groups x 17 frame-tiles
#define INVW_BLOCKS 512

// Permuted ("tile-fragment") global layout for Ap and Bp, 16B chunks of 8 bf16:
//   chunk16B(row, kc) = (row>>4)*1024 + kc*16 + (row&15),  kc = k/8 in [0,64)
// GEMM staging reads contiguous 1KB per wave AND LDS lands in MFMA fragment
// order (ds_read_b128 conflict-free; verified rounds 2-13).

// prep branch order: LONGEST-latency bodies first so they overlap the rest
#define BURG_BLOCKS   512
#define FRAMES_BLOCKS 2080   // 520 row-blocks x 4 kc-groups
#define BASIS_BLOCKS  512    // 2048*64/256
#define SARR_BLOCKS   17     // 4352 S entries (also zeroes accumulators)
#define PREP_BLOCKS   (BURG_BLOCKS + FRAMES_BLOCKS + BASIS_BLOCKS + SARR_BLOCKS)

typedef __attribute__((ext_vector_type(8))) short short8;
typedef __attribute__((ext_vector_type(4))) short short4v;
typedef __attribute__((ext_vector_type(4))) float floatx4;
typedef float floatx4u __attribute__((ext_vector_type(4), aligned(4)));   // 4B-aligned vec load

typedef __attribute__((address_space(1))) void gvoid_as1;
typedef __attribute__((address_space(3))) void lvoid_as3;

__device__ __forceinline__ void gld_lds16(const void* g, void* l) {
    __builtin_amdgcn_global_load_lds((gvoid_as1*)g, (lvoid_as3*)l, 16, 0, 0);
}

__device__ __forceinline__ float b2f(short v) {
    unsigned int u = ((unsigned int)(unsigned short)v) << 16;
    return __uint_as_float(u);
}

__device__ __forceinline__ float xorall(float v) {
    v += __shfl_xor(v, 1, 64);
    v += __shfl_xor(v, 2, 64);
    v += __shfl_xor(v, 4, 64);
    v += __shfl_xor(v, 8, 64);
    v += __shfl_xor(v, 16, 64);
    v += __shfl_xor(v, 32, 64);
    return v;
}

__device__ __forceinline__ float wave_reduce(float v) {
    v += __shfl_down(v, 32, 64);
    v += __shfl_down(v, 16, 64);
    v += __shfl_down(v, 8, 64);
    v += __shfl_down(v, 4, 64);
    v += __shfl_down(v, 2, 64);
    v += __shfl_down(v, 1, 64);
    return v;
}

// ---------------- frames branch: build Ap (bf16, permuted chunk layout) ----------------
// Ap[row=2b+s][n] = xp_s[511b + n], n<511 (col 511 = 0).
// Lane map: 16-lane group = 16 consecutive kc of ONE row -> contiguous 512B reads.
__device__ __forceinline__ void frames_body(int bid, int tid,
                                            const float* __restrict__ x,
                                            const float* __restrict__ y,
                                            __hip_bfloat16* __restrict__ A) {
    const int rb = bid >> 2;
    const int kc = (bid & 3) * 16 + (tid & 15);
    const int rowIn = tid >> 4;
    const int row = rb * 16 + rowIn;
    const int ci = rb * 1024 + kc * 16 + rowIn;      // permuted chunk index
    __hip_bfloat16 tmp[8];
    if (row < MROWS_P) {
        const int b = row >> 1;
        const float* src = (row & 1) ? y : x;
        const int p0 = b * 511 + kc * 8 - 1023;      // xp index of element 0
        if (kc < 63 && p0 >= 0 && p0 + 8 <= L_TOTAL) {
            // interior fast path: two vectorized loads (4B-aligned ok)
            floatx4u v0 = *(const floatx4u*)(src + p0);
            floatx4u v1 = *(const floatx4u*)(src + p0 + 4);
#pragma unroll
            for (int e = 0; e < 4; e++) tmp[e] = __float2bfloat16(v0[e]);
#pragma unroll
            for (int e = 0; e < 4; e++) tmp[4 + e] = __float2bfloat16(v1[e]);
        } else {
#pragma unroll
            for (int e = 0; e < 8; e++) {
                const int n = kc * 8 + e;
                float v = 0.f;
                if (n < 511) {
                    int p = p0 + e;
                    if (p < 0) p = -p;
                    else if (p >= L_TOTAL) p = 2 * L_TOTAL - 2 - p;
                    v = src[p];
                }
                tmp[e] = __float2bfloat16(v);
            }
        }
    } else {
#pragma unroll
        for (int e = 0; e < 8; e++) tmp[e] = __float2bfloat16(0.f);
    }
    *(short8*)((char*)A + (size_t)ci * 16) = *(short8*)tmp;
}

// ---------------- basis branch: Bp (bf16, permuted chunk layout) ----------------
// rotation recurrence: sincos at n0 and step, then 7 complex rotations.
__device__ __forceinline__ void basis_body(int bid, int tid,
                                           __hip_bfloat16* __restrict__ Bt) {
    const int ci = bid * 256 + tid;
    const int rb = ci >> 10;
    const int kc = (ci >> 4) & 63;
    const int rowIn = ci & 15;
    const int row = rb * 16 + rowIn;
    const int f = row >> 1;
    const bool isSin = row & 1;
    const int n0 = kc * 8;
    const int m0 = (f * n0) % 2046;          // exact angle mod 2pi at n0
    float s, c, ss, cs;
    __sincosf((float)m0 * (float)(PI_D / 1023.0), &s, &c);
    __sincosf((float)f * (float)(PI_D / 1023.0), &ss, &cs);
    __hip_bfloat16 tmp[8];
#pragma unroll
    for (int e = 0; e < 8; e++) {
        const int n = n0 + e;
        float v = isSin ? -s : c;
        if (n >= 511) v = 0.f;
        tmp[e] = __float2bfloat16(v);
        float c2 = c * cs - s * ss;          // angle += f*pi/1023
        float s2 = s * cs + c * ss;
        c = c2; s = s2;
    }
    *(short8*)((char*)Bt + (size_t)ci * 16) = *(short8*)tmp;
}

// ---------------- S branch: tail-sample table + accumulator zeroing ----------------
__device__ __forceinline__ void sarr_body(int bid, int tid,
                                          const float* __restrict__ x,
                                          const float* __restrict__ y,
                                          float4* __restrict__ S,
                                          float* __restrict__ wsf) {
    if (bid < 8) wsf[bid * 256 + tid] = 0.f;   // zero mse_sum + invW
    const int b = bid * 256 + tid;          // 0..4351
    int p0 = 511 * b - 1023;
    int p1 = p0 + 1;
    int m0 = (p0 < 0) ? -p0 : ((p0 >= L_TOTAL) ? 2 * L_TOTAL - 2 - p0 : p0);
    int m1 = (p1 < 0) ? -p1 : ((p1 >= L_TOTAL) ? 2 * L_TOTAL - 2 - p1 : p1);
    S[b] = make_float4(x[m0], x[m1], y[m0], y[m1]);
}

// ---------------- burg branch: one WAVE per 1024-sample audio block ----------------
__device__ __forceinline__ void burg_body(int bid, int tid,
                                          const float* __restrict__ y,
                                          float* __restrict__ ar_out) {
    const int lane = tid & 63;
    const int wid = tid >> 6;
    const int blk = bid * 4 + wid;
    const float4* yb4 = (const float4*)(y + (size_t)blk * 1024) + lane * 4;

    float t[16];
#pragma unroll
    for (int q = 0; q < 4; q++) {
        float4 v = yb4[q];
        t[q * 4 + 0] = v.x; t[q * 4 + 1] = v.y;
        t[q * 4 + 2] = v.z; t[q * 4 + 3] = v.w;
    }
    float b[16], f[16];
#pragma unroll
    for (int r = 0; r < 16; r++) b[r] = t[r];
#pragma unroll
    for (int r = 0; r < 15; r++) f[r] = t[r + 1];
    {
        float nb = __shfl_down(t[0], 1, 64);
        f[15] = (lane == 63) ? 0.f : nb;
        if (lane == 63) b[15] = 0.f;
    }

    float den = 0.f;
#pragma unroll
    for (int r = 0; r < 16; r++) den += f[r] * f[r] + b[r] * b[r];
    den = xorall(den);

    float ar_s[13];
    ar_s[0] = 1.f;
#pragma unroll
    for (int j = 1; j < 13; j++) ar_s[j] = 0.f;

#pragma unroll
    for (int i = 0; i < 12; i++) {
        float num = 0.f;
#pragma unroll
        for (int r = 0; r < 16; r++) num += f[r] * b[r];
        num = xorall(num);
        const float k = -2.f * num / den;

        float fu[16], bu[16];
#pragma unroll
        for (int r = 0; r < 16; r++) {
            fu[r] = f[r] + k * b[r];
            bu[r] = b[r] + k * f[r];
        }
        const float f0 = __shfl(fu[0], 0, 64);
        const int pos = 1022 - i;
        const int L = pos >> 4, S = pos & 15;
        const float blast = __shfl(bu[S], L, 64);

        den = (1.f - k * k) * den - blast * blast - f0 * f0;

        float nf = __shfl_down(fu[0], 1, 64);
#pragma unroll
        for (int r = 0; r < 15; r++) f[r] = fu[r + 1];
        f[15] = (lane == 63) ? 0.f : nf;
#pragma unroll
        for (int r = 0; r < 16; r++) b[r] = bu[r];
        if (lane == L) b[S] = 0.f;

        float tmp[13];
#pragma unroll
        for (int js = 1; js <= i + 1; js++) tmp[js] = ar_s[js] + k * ar_s[i + 1 - js];
#pragma unroll
        for (int js = 1; js <= i + 1; js++) ar_s[js] = tmp[js];
    }

#pragma unroll
    for (int j = 0; j < 12; j++)
        if (lane == j) ar_out[(size_t)blk * 12 + j] = ar_s[j];
}

// ---------------- fused prep: burg FIRST (longest-latency), then frames/basis/S -----
__global__ __launch_bounds__(256) void prep_kernel(const float* __restrict__ x,
                                                   const float* __restrict__ y,
                                                   __hip_bfloat16* __restrict__ A,
                                                   __hip_bfloat16* __restrict__ Bt,
                                                   float4* __restrict__ S,
                                                   float* __restrict__ ar,
                                                   float* __restrict__ wsf) {
    const int bid = blockIdx.x;
    const int tid = threadIdx.x;
    if (bid < BURG_BLOCKS) {
        burg_body(bid, tid, y, ar);
    } else if (bid < BURG_BLOCKS + FRAMES_BLOCKS) {
        frames_body(bid - BURG_BLOCKS, tid, x, y, A);
    } else if (bid < BURG_BLOCKS + FRAMES_BLOCKS + BASIS_BLOCKS) {
        basis_body(bid - BURG_BLOCKS - FRAMES_BLOCKS, tid, Bt);
    } else {
        sarr_body(bid - BURG_BLOCKS - FRAMES_BLOCKS - BASIS_BLOCKS, tid, x, y, S, wsf);
    }
}

// ---------------- P-GEMM (8 waves / 512 threads per 128x128 tile) ----------------
// Each wave: 32x64 sub-tile, acc 2x4 (32 AGPR). (512,4) = 2 blocks/CU, 16 waves/CU
// -- the proven round-12 configuration; (512,6) regressed (r13). Staging: 1 A-chunk
// + 1 B-chunk per thread per K-iter, contiguous 1KB per wave, fragment-ordered LDS.
__global__ __launch_bounds__(512, 4) void gemm_p_kernel(
    const __hip_bfloat16* __restrict__ A, const __hip_bfloat16* __restrict__ Bt,
    __hip_bfloat16* __restrict__ Pt) {
    __shared__ __align__(16) __hip_bfloat16 Al[128 * 32];
    __shared__ __align__(16) __hip_bfloat16 Bl[128 * 32];

    const int tid = threadIdx.x;        // 0..511
    const int lane = tid & 63;
    const int w = tid >> 6;             // 0..7
    const int wm = w >> 1;              // 0..3: 32-row slab
    const int wn = w & 1;               // 0..1: 64-col slab
    const int q = lane >> 4, l15 = lane & 15;
    const int tileN = blockIdx.x * 128;
    const int tileM = blockIdx.y * 128;

    floatx4 acc[2][4];
#pragma unroll
    for (int i = 0; i < 2; i++)
#pragma unroll
        for (int j = 0; j < 4; j++) acc[i][j] = (floatx4){0.f, 0.f, 0.f, 0.f};

    const int gg = tid >> 6;            // row-block 0..7
    const int inner = tid & 63;
    const char* pA = (const char*)A + ((((size_t)(tileM >> 4) + gg) << 10) + inner) * 16;
    const char* pB = (const char*)Bt + ((((size_t)(tileN >> 4) + gg) << 10) + inner) * 16;
    char* AlB = (char*)Al;
    char* BlB = (char*)Bl;

    for (int it = 0; it < KP / 32; it++) {
        gld_lds16(pA, AlB + tid * 16);
        gld_lds16(pB, BlB + tid * 16);
        pA += 1024; pB += 1024;        // 64 chunks per row-block per K-step of 32
        __syncthreads();

        short8 af[2], bf[4];
#pragma unroll
        for (int sm = 0; sm < 2; sm++)
            af[sm] = *(const short8*)(AlB + (((wm * 2 + sm) * 64 + lane) * 16));
#pragma unroll
        for (int sn = 0; sn < 4; sn++)
            bf[sn] = *(const short8*)(BlB + (((wn * 4 + sn) * 64 + lane) * 16));
#pragma unroll
        for (int sm = 0; sm < 2; sm++)
#pragma unroll
            for (int sn = 0; sn < 4; sn++)
                acc[sm][sn] = __builtin_amdgcn_mfma_f32_16x16x32_bf16(
                    af[sm], bf[sn], acc[sm][sn], 0, 0, 0);
        __syncthreads();
    }

    // epilogue: C/D col=lane&15 (N), row=quad*4+reg (M). Write Pt[n][m] bf16.
#pragma unroll
    for (int sm = 0; sm < 2; sm++) {
        const int rowBase = tileM + wm * 32 + sm * 16 + q * 4;
        if (rowBase >= MROWS_P) continue;      // pad rows
#pragma unroll
        for (int sn = 0; sn < 4; sn++) {
            const int colG = tileN + wn * 64 + sn * 16 + l15;
            short4v pk;
#pragma unroll
            for (int r = 0; r < 4; r++) {
                __hip_bfloat16 h = __float2bfloat16(acc[sm][sn][r]);
                pk[r] = *(short*)&h;
            }
            *(short4v*)((char*)Pt + ((size_t)colG * PSTRIDE + rowBase) * 2) = pk;
        }
    }
}

// ---------------- combine body: X_t[f] = sum_h W_h P_{t+h}[f] + tail; mse ----------
__device__ __forceinline__ void combine_body(int bx, int ty, int tid,
                                             const __hip_bfloat16* __restrict__ Pt,
                                             const float4* __restrict__ S,
                                             float* __restrict__ mse_sum) {
    const int lane = tid & 63;
    const int wid = tid >> 6;
    const int f = bx * 4 + wid;              // 0..1023

    // twiddles: W_h = e^{-2pi i f*511h/2046}; tails at offsets 2044, 2045
    float wc[4], ws[4];
    wc[0] = 1.f; ws[0] = 0.f;
#pragma unroll
    for (int h = 1; h < 4; h++) {
        int m = (511 * h * f) % 2046;
        float s, c;
        __sincosf((float)m * (float)(PI_D / 1023.0), &s, &c);
        wc[h] = c; ws[h] = -s;
    }
    float wtc0, wts0, wtc1, wts1;
    {
        int m = (2044 * f) % 2046;
        float s, c;
        __sincosf((float)m * (float)(PI_D / 1023.0), &s, &c);
        wtc0 = c; wts0 = -s;
        m = (2045 * f) % 2046;
        __sincosf((float)m * (float)(PI_D / 1023.0), &s, &c);
        wtc1 = c; wts1 = -s;
    }

    const __hip_bfloat16* rowRe = Pt + (size_t)(2 * f) * PSTRIDE;
    const __hip_bfloat16* rowIm = rowRe + PSTRIDE;

    float acc = 0.f;
    const int tt0 = ty * 256 + 4 * lane;
    if (tt0 < NFRAMES) {
        short8 re0 = *(const short8*)(rowRe + 2 * tt0);
        short8 re1 = *(const short8*)(rowRe + 2 * tt0 + 8);
        short8 im0 = *(const short8*)(rowIm + 2 * tt0);
        short8 im1 = *(const short8*)(rowIm + 2 * tt0 + 8);
        float4 sT[4];
#pragma unroll
        for (int d = 0; d < 4; d++) sT[d] = S[tt0 + 4 + d];   // contiguous across wave
        float vr[16], vi[16];
#pragma unroll
        for (int j = 0; j < 8; j++) {
            vr[j] = b2f(re0[j]); vr[j + 8] = b2f(re1[j]);
            vi[j] = b2f(im0[j]); vi[j + 8] = b2f(im1[j]);
        }
#pragma unroll
        for (int d = 0; d < 4; d++) {
            const int tt = tt0 + d;
            if (tt >= NFRAMES) break;
            float xr = 0.f, xi = 0.f, yr = 0.f, yi = 0.f;
#pragma unroll
            for (int h = 0; h < 4; h++) {
                const int qx = 2 * d + 2 * h;
                xr += wc[h] * vr[qx] - ws[h] * vi[qx];
                xi += wc[h] * vi[qx] + ws[h] * vr[qx];
                const int qy = qx + 1;
                yr += wc[h] * vr[qy] - ws[h] * vi[qy];
                yi += wc[h] * vi[qy] + ws[h] * vr[qy];
            }
            const float4 sd = sT[d];
            xr += wtc0 * sd.x + wtc1 * sd.y;
            xi += wts0 * sd.x + wts1 * sd.y;
            yr += wtc0 * sd.z + wtc1 * sd.w;
            yi += wts0 * sd.z + wts1 * sd.w;
            float dm = sqrtf(xr * xr + xi * xi) - sqrtf(yr * yr + yi * yi);
            acc += dm * dm;
        }
    }
    acc = xorall(acc);
    if (lane == 0) atomicAdd(&mse_sum[f], acc);
}

// ---------------- invw body: invW[f] += sum_{b in 16-group, kk} |den|/|num| --------
__device__ __forceinline__ void invw_body(int bid, int tid,
                                          const float* __restrict__ ar,
                                          float* __restrict__ invW) {
    __shared__ float sar[16][12];
    const int f = (bid & 3) * 256 + tid;
    const int b0 = (bid >> 2) * 16;
    if (tid < 16 * 12) ((float*)sar)[tid] = ar[(size_t)b0 * 12 + tid];
    __syncthreads();

    const float omega = (float)(PI_D / 1024.0) * (float)f;
    float sw, cw;
    __sincosf(omega, &sw, &cw);

    float acc = 0.f;
#pragma unroll 4
    for (int bb = 0; bb < 16; bb++) {
        float a0 = sar[bb][0];
        float nr = a0, ni = 0.f, dr = a0, di = 0.f;
        float er = 1.f, ei = 0.f;
        float g1p = 1.f, g2p = 1.f;
#pragma unroll
        for (int j = 1; j < 12; j++) {
            float er2 = er * cw + ei * sw;
            float ei2 = ei * cw - er * sw;
            er = er2; ei = ei2;
            g1p *= 0.92f; g2p *= 0.6f;
            float aj = sar[bb][j];
            float a1 = aj * g1p, a2 = aj * g2p;
            nr += a2 * er; ni += a2 * ei;
            dr += a1 * er; di += a1 * ei;
            float D = dr * dr + di * di;
            float Nn = nr * nr + ni * ni;
            acc += D * __builtin_amdgcn_rsqf(D * Nn);
        }
    }
    atomicAdd(&invW[f], acc);
}

// ---------------- fused invW (FIRST, long-latency) + combine dispatch ----------------
__global__ __launch_bounds__(256) void combine_invw_kernel(
    const __hip_bfloat16* __restrict__ Pt,
    const float4* __restrict__ S,
    float* __restrict__ mse_sum,
    const float* __restrict__ ar,
    float* __restrict__ invW) {
    const int bid = blockIdx.x;
    const int tid = threadIdx.x;
    if (bid < INVW_BLOCKS) {
        invw_body(bid, tid, ar, invW);
    } else {
        const int cb = bid - INVW_BLOCKS;
        combine_body(cb & 255, cb >> 8, tid, Pt, S, mse_sum);
    }
}

// ---------------- final: out = sum_f mse_sum[f]*invW[f] / (4105*22528*1024) ----------------
__global__ void final_kernel(const float* __restrict__ mse_sum,
                             const float* __restrict__ invW,
                             float* __restrict__ out) {
    __shared__ float red[4];
    const int tid = threadIdx.x;
    float lo = 0.f;
    for (int f = tid; f < 1024; f += 256) lo += mse_sum[f] * invW[f];
    lo = wave_reduce(lo);
    if ((tid & 63) == 0) red[tid >> 6] = lo;
    __syncthreads();
    if (tid == 0) {
        float tot = red[0] + red[1] + red[2] + red[3];
        out[0] = tot * (float)(1.0 / (4105.0 * 22528.0 * 1024.0));
    }
}

extern "C" void kernel_launch(void* const* d_in, const int* in_sizes, int n_in,
                              void* d_out, int out_size, void* d_ws, size_t ws_size,
                              hipStream_t stream) {
    const float* x = (const float*)d_in[0];
    const float* y = (const float*)d_in[1];
    float* out = (float*)d_out;

    float* wsf = (float*)d_ws;
    float* mse_sum = wsf;                    // [0,1024) floats
    float* invW = wsf + 1024;                // [1024,2048)
    float* ar = wsf + 2080;                  // 2048*12 floats -> ends byte 106624
    float4* S = (float4*)((char*)d_ws + 131072);                     // 4352*16 = 69,632 B
    __hip_bfloat16* Ap = (__hip_bfloat16*)((char*)d_ws + 262144);    // 8320*512*2 = 8,519,680 B
    __hip_bfloat16* Bp = (__hip_bfloat16*)((char*)d_ws + 8781824);   // 2048*512*2 = 2,097,152 B
    __hip_bfloat16* Pt = (__hip_bfloat16*)((char*)d_ws + 10878976);  // 2048*8224*2 = 33,685,504 B

    prep_kernel<<<PREP_BLOCKS, 256, 0, stream>>>(x, y, Ap, Bp, S, ar, wsf);
    gemm_p_kernel<<<dim3(NDIM / 128, MPAD / 128), 512, 0, stream>>>(Ap, Bp, Pt);
    combine_invw_kernel<<<INVW_BLOCKS + COMBINE_BLOCKS, 256, 0, stream>>>(Pt, S, mse_sum, ar, invW);
    final_kernel<<<1, 256, 0, stream>>>(mse_sum, invW, out);
}

// Round 15
// 125.379 us; speedup vs baseline: 1.0610x; 1.0147x over previous
//
#include <hip/hip_runtime.h>
#include <hip/hip_bf16.h>
#include <hip/hip_fp8.h>

#define PI_D 3.14159265358979323846
#define L_TOTAL 2097152
#define NFRAMES 4105      // 1 + L/511
#define NBLK    4108      // hop-blocks b: frames t use blocks t..t+3 + 2 samples of t+4
#define MROWS_P 8216      // 2*NBLK (x/y interleaved)
#define MPAD    8320      // 65 * 128
#define KP      512       // 511 padded
#define NDIM    2048      // 1024 bins * (Re,Im)
#define PSTRIDE 8224      // Pt row stride (>= MROWS_P + 8 slack, 16B aligned)

#define COMBINE_BLOCKS 4352   // 256 f-groups x 17 frame-tiles
#define INVW_BLOCKS 512

// fp8 (OCP e4m3) permuted global layout for Ap and Bp, in 8B units of 8 fp8:
//   unit8(row, kc) = (row>>4)*1024 + kc*16 + (row&15),  kc = k/8 in [0,64)
// A 16B store covers rows (2b, 2b+1) = (x,y) same k-range. GEMM staging is a
// linear copy (contiguous 512B per wave), LDS fragment read = rowblk*512 +
// lane*8 (ds_read_b64, conflict-free). K=511 pad column zeroed in B only.

// prep branch order: LONGEST-latency bodies first so they overlap the rest
#define BURG_BLOCKS   512
#define FRAMES_BLOCKS 1040   // 4160 waves, one per hop-block (pad rows harmless)
#define BASIS_BLOCKS  256    // 1024 waves, one per frequency f
#define SARR_BLOCKS   17     // 4352 S entries (also zeroes accumulators)
#define PREP_BLOCKS   (BURG_BLOCKS + FRAMES_BLOCKS + BASIS_BLOCKS + SARR_BLOCKS)

typedef __attribute__((ext_vector_type(8))) short short8;
typedef __attribute__((ext_vector_type(4))) short short4v;
typedef __attribute__((ext_vector_type(4))) float floatx4;
typedef float floatx4u __attribute__((ext_vector_type(4), aligned(4)));   // 4B-aligned vec load

typedef __attribute__((address_space(1))) void gvoid_as1;
typedef __attribute__((address_space(3))) void lvoid_as3;

__device__ __forceinline__ void gld_lds16(const void* g, void* l) {
    __builtin_amdgcn_global_load_lds((gvoid_as1*)g, (lvoid_as3*)l, 16, 0, 0);
}

__device__ __forceinline__ float b2f(short v) {
    unsigned int u = ((unsigned int)(unsigned short)v) << 16;
    return __uint_as_float(u);
}

__device__ __forceinline__ unsigned int pk4_e4m3(float a, float b, float c, float d) {
    __hip_fp8_e4m3 q0(a), q1(b), q2(c), q3(d);
    return (unsigned int)q0.__x | ((unsigned int)q1.__x << 8)
         | ((unsigned int)q2.__x << 16) | ((unsigned int)q3.__x << 24);
}

__device__ __forceinline__ float xorall(float v) {
    v += __shfl_xor(v, 1, 64);
    v += __shfl_xor(v, 2, 64);
    v += __shfl_xor(v, 4, 64);
    v += __shfl_xor(v, 8, 64);
    v += __shfl_xor(v, 16, 64);
    v += __shfl_xor(v, 32, 64);
    return v;
}

__device__ __forceinline__ float wave_reduce(float v) {
    v += __shfl_down(v, 32, 64);
    v += __shfl_down(v, 16, 64);
    v += __shfl_down(v, 8, 64);
    v += __shfl_down(v, 4, 64);
    v += __shfl_down(v, 2, 64);
    v += __shfl_down(v, 1, 64);
    return v;
}

// ---------------- frames branch: build Ap (fp8 e4m3, permuted layout) --------------
// one WAVE per hop-block b; lane covers k = lane*8..+8 of both x and y rows.
// Reads: one contiguous ~2KB run per signal per wave. k=511 pad left non-zero
// (B zeroes it); rows >= MROWS_P are pad (never read in epilogue).
__device__ __forceinline__ void frames_body(int bid, int tid,
                                            const float* __restrict__ x,
                                            const float* __restrict__ y,
                                            char* __restrict__ A) {
    const int lane = tid & 63;
    const int b = bid * 4 + (tid >> 6);          // 0..4159
    const int p0 = b * 511 + lane * 8 - 1023;    // xp index of element 0
    float xv[8], yv[8];
    if (p0 >= 0 && p0 + 8 <= L_TOTAL) {
        floatx4u x0 = *(const floatx4u*)(x + p0);
        floatx4u x1 = *(const floatx4u*)(x + p0 + 4);
        floatx4u y0 = *(const floatx4u*)(y + p0);
        floatx4u y1 = *(const floatx4u*)(y + p0 + 4);
#pragma unroll
        for (int e = 0; e < 4; e++) { xv[e] = x0[e]; xv[4 + e] = x1[e]; }
#pragma unroll
        for (int e = 0; e < 4; e++) { yv[e] = y0[e]; yv[4 + e] = y1[e]; }
    } else {
#pragma unroll
        for (int e = 0; e < 8; e++) {
            int p = p0 + e;
            if (p < 0) p = -p;
            else if (p >= L_TOTAL) p = 2 * L_TOTAL - 2 - p;
            xv[e] = x[p];
            yv[e] = y[p];
        }
    }
    int4 pk;
    pk.x = (int)pk4_e4m3(xv[0], xv[1], xv[2], xv[3]);
    pk.y = (int)pk4_e4m3(xv[4], xv[5], xv[6], xv[7]);
    pk.z = (int)pk4_e4m3(yv[0], yv[1], yv[2], yv[3]);
    pk.w = (int)pk4_e4m3(yv[4], yv[5], yv[6], yv[7]);
    *(int4*)(A + (size_t)(b >> 3) * 8192 + lane * 128 + (b & 7) * 16) = pk;
}

// ---------------- basis branch: Bp (fp8 e4m3, permuted layout) ---------------------
// one WAVE per frequency f; lane covers k = lane*8..+8 of rows (2f=cos, 2f+1=-sin).
// n=511 zeroed here (neutralizes A's pad column).
__device__ __forceinline__ void basis_body(int bid, int tid,
                                           char* __restrict__ Bt) {
    const int lane = tid & 63;
    const int f = bid * 4 + (tid >> 6);          // 0..1023
    const int n0 = lane * 8;
    const int m0 = (f * n0) % 2046;              // exact angle mod 2pi
    float s, c, ss, cs;
    __sincosf((float)m0 * (float)(PI_D / 1023.0), &s, &c);
    __sincosf((float)f * (float)(PI_D / 1023.0), &ss, &cs);
    float cv[8], sv[8];
#pragma unroll
    for (int e = 0; e < 8; e++) {
        const int n = n0 + e;
        const bool valid = n < 511;
        cv[e] = valid ? c : 0.f;
        sv[e] = valid ? -s : 0.f;
        float c2 = c * cs - s * ss;              // angle += f*pi/1023
        float s2 = s * cs + c * ss;
        c = c2; s = s2;
    }
    int4 pk;
    pk.x = (int)pk4_e4m3(cv[0], cv[1], cv[2], cv[3]);
    pk.y = (int)pk4_e4m3(cv[4], cv[5], cv[6], cv[7]);
    pk.z = (int)pk4_e4m3(sv[0], sv[1], sv[2], sv[3]);
    pk.w = (int)pk4_e4m3(sv[4], sv[5], sv[6], sv[7]);
    *(int4*)(Bt + (size_t)(f >> 3) * 8192 + lane * 128 + (f & 7) * 16) = pk;
}

// ---------------- S branch: tail-sample table + accumulator zeroing ----------------
__device__ __forceinline__ void sarr_body(int bid, int tid,
                                          const float* __restrict__ x,
                                          const float* __restrict__ y,
                                          float4* __restrict__ S,
                                          float* __restrict__ wsf) {
    if (bid < 8) wsf[bid * 256 + tid] = 0.f;   // zero mse_sum + invW
    const int b = bid * 256 + tid;          // 0..4351
    int p0 = 511 * b - 1023;
    int p1 = p0 + 1;
    int m0 = (p0 < 0) ? -p0 : ((p0 >= L_TOTAL) ? 2 * L_TOTAL - 2 - p0 : p0);
    int m1 = (p1 < 0) ? -p1 : ((p1 >= L_TOTAL) ? 2 * L_TOTAL - 2 - p1 : p1);
    S[b] = make_float4(x[m0], x[m1], y[m0], y[m1]);
}

// ---------------- burg branch: one WAVE per 1024-sample audio block ----------------
__device__ __forceinline__ void burg_body(int bid, int tid,
                                          const float* __restrict__ y,
                                          float* __restrict__ ar_out) {
    const int lane = tid & 63;
    const int wid = tid >> 6;
    const int blk = bid * 4 + wid;
    const float4* yb4 = (const float4*)(y + (size_t)blk * 1024) + lane * 4;

    float t[16];
#pragma unroll
    for (int q = 0; q < 4; q++) {
        float4 v = yb4[q];
        t[q * 4 + 0] = v.x; t[q * 4 + 1] = v.y;
        t[q * 4 + 2] = v.z; t[q * 4 + 3] = v.w;
    }
    float b[16], f[16];
#pragma unroll
    for (int r = 0; r < 16; r++) b[r] = t[r];
#pragma unroll
    for (int r = 0; r < 15; r++) f[r] = t[r + 1];
    {
        float nb = __shfl_down(t[0], 1, 64);
        f[15] = (lane == 63) ? 0.f : nb;
        if (lane == 63) b[15] = 0.f;
    }

    float den = 0.f;
#pragma unroll
    for (int r = 0; r < 16; r++) den += f[r] * f[r] + b[r] * b[r];
    den = xorall(den);

    float ar_s[13];
    ar_s[0] = 1.f;
#pragma unroll
    for (int j = 1; j < 13; j++) ar_s[j] = 0.f;

#pragma unroll
    for (int i = 0; i < 12; i++) {
        float num = 0.f;
#pragma unroll
        for (int r = 0; r < 16; r++) num += f[r] * b[r];
        num = xorall(num);
        const float k = -2.f * num / den;

        float fu[16], bu[16];
#pragma unroll
        for (int r = 0; r < 16; r++) {
            fu[r] = f[r] + k * b[r];
            bu[r] = b[r] + k * f[r];
        }
        const float f0 = __shfl(fu[0], 0, 64);
        const int pos = 1022 - i;
        const int L = pos >> 4, S = pos & 15;
        const float blast = __shfl(bu[S], L, 64);

        den = (1.f - k * k) * den - blast * blast - f0 * f0;

        float nf = __shfl_down(fu[0], 1, 64);
#pragma unroll
        for (int r = 0; r < 15; r++) f[r] = fu[r + 1];
        f[15] = (lane == 63) ? 0.f : nf;
#pragma unroll
        for (int r = 0; r < 16; r++) b[r] = bu[r];
        if (lane == L) b[S] = 0.f;

        float tmp[13];
#pragma unroll
        for (int js = 1; js <= i + 1; js++) tmp[js] = ar_s[js] + k * ar_s[i + 1 - js];
#pragma unroll
        for (int js = 1; js <= i + 1; js++) ar_s[js] = tmp[js];
    }

#pragma unroll
    for (int j = 0; j < 12; j++)
        if (lane == j) ar_out[(size_t)blk * 12 + j] = ar_s[j];
}

// ---------------- fused prep: burg FIRST (longest-latency), then frames/basis/S -----
__global__ __launch_bounds__(256) void prep_kernel(const float* __restrict__ x,
                                                   const float* __restrict__ y,
                                                   char* __restrict__ A,
                                                   char* __restrict__ Bt,
                                                   float4* __restrict__ S,
                                                   float* __restrict__ ar,
                                                   float* __restrict__ wsf) {
    const int bid = blockIdx.x;
    const int tid = threadIdx.x;
    if (bid < BURG_BLOCKS) {
        burg_body(bid, tid, y, ar);
    } else if (bid < BURG_BLOCKS + FRAMES_BLOCKS) {
        frames_body(bid - BURG_BLOCKS, tid, x, y, A);
    } else if (bid < BURG_BLOCKS + FRAMES_BLOCKS + BASIS_BLOCKS) {
        basis_body(bid - BURG_BLOCKS - FRAMES_BLOCKS, tid, Bt);
    } else {
        sarr_body(bid - BURG_BLOCKS - FRAMES_BLOCKS - BASIS_BLOCKS, tid, x, y, S, wsf);
    }
}

// ---------------- P-GEMM fp8 (8 waves / 512 threads per 128x128 tile) --------------
// Each wave: 32x64 sub-tile via mfma_f32_16x16x32_fp8_fp8 (i64 operands).
// Staging: ONE 16B global_load_lds per thread per K-step (8KB/iter total),
// contiguous 512B per wave, fragment-ordered LDS (ds_read_b64, 0 conflicts).
__global__ __launch_bounds__(512, 4) void gemm_p_kernel(
    const char* __restrict__ A, const char* __restrict__ Bt,
    __hip_bfloat16* __restrict__ Pt) {
    __shared__ __align__(16) char smem[8192];   // A: [0,4096), B: [4096,8192)

    const int tid = threadIdx.x;        // 0..511
    const int lane = tid & 63;
    const int w = tid >> 6;             // 0..7
    const int wm = w >> 1;              // 0..3: 32-row slab
    const int wn = w & 1;               // 0..1: 64-col slab
    const int q = lane >> 4, l15 = lane & 15;
    const int tileN = blockIdx.x * 128;
    const int tileM = blockIdx.y * 128;

    floatx4 acc[2][4];
#pragma unroll
    for (int i = 0; i < 2; i++)
#pragma unroll
        for (int j = 0; j < 4; j++) acc[i][j] = (floatx4){0.f, 0.f, 0.f, 0.f};

    const int t8 = tid & 255;
    const int g = t8 >> 5;              // row/col-block 0..7
    const int u = t8 & 31;              // 16B unit within K-step
    const char* p = ((tid < 256)
        ? A + (((size_t)(tileM >> 4) + g) << 13)
        : Bt + (((size_t)(tileN >> 4) + g) << 13)) + u * 16;

    for (int it = 0; it < KP / 32; it++) {
        gld_lds16(p, smem + tid * 16);
        p += 512;                       // next K-step of 32 (4 kc units)
        __syncthreads();

        long af[2], bf[4];
#pragma unroll
        for (int sm = 0; sm < 2; sm++)
            af[sm] = *(const long*)(smem + (wm * 2 + sm) * 512 + lane * 8);
#pragma unroll
        for (int sn = 0; sn < 4; sn++)
            bf[sn] = *(const long*)(smem + 4096 + (wn * 4 + sn) * 512 + lane * 8);
#pragma unroll
        for (int sm = 0; sm < 2; sm++)
#pragma unroll
            for (int sn = 0; sn < 4; sn++)
                acc[sm][sn] = __builtin_amdgcn_mfma_f32_16x16x32_fp8_fp8(
                    af[sm], bf[sn], acc[sm][sn], 0, 0, 0);
        __syncthreads();
    }

    // epilogue: C/D col=lane&15 (N), row=quad*4+reg (M). Write Pt[n][m] bf16.
#pragma unroll
    for (int sm = 0; sm < 2; sm++) {
        const int rowBase = tileM + wm * 32 + sm * 16 + q * 4;
        if (rowBase >= MROWS_P) continue;      // pad rows
#pragma unroll
        for (int sn = 0; sn < 4; sn++) {
            const int colG = tileN + wn * 64 + sn * 16 + l15;
            short4v pk;
#pragma unroll
            for (int r = 0; r < 4; r++) {
                __hip_bfloat16 h = __float2bfloat16(acc[sm][sn][r]);
                pk[r] = *(short*)&h;
            }
            *(short4v*)((char*)Pt + ((size_t)colG * PSTRIDE + rowBase) * 2) = pk;
        }
    }
}

// ---------------- combine body: X_t[f] = sum_h W_h P_{t+h}[f] + tail; mse ----------
__device__ __forceinline__ void combine_body(int bx, int ty, int tid,
                                             const __hip_bfloat16* __restrict__ Pt,
                                             const float4* __restrict__ S,
                                             float* __restrict__ mse_sum) {
    const int lane = tid & 63;
    const int wid = tid >> 6;
    const int f = bx * 4 + wid;              // 0..1023

    // twiddles: W_h = e^{-2pi i f*511h/2046}; tails at offsets 2044, 2045
    float wc[4], ws[4];
    wc[0] = 1.f; ws[0] = 0.f;
#pragma unroll
    for (int h = 1; h < 4; h++) {
        int m = (511 * h * f) % 2046;
        float s, c;
        __sincosf((float)m * (float)(PI_D / 1023.0), &s, &c);
        wc[h] = c; ws[h] = -s;
    }
    float wtc0, wts0, wtc1, wts1;
    {
        int m = (2044 * f) % 2046;
        float s, c;
        __sincosf((float)m * (float)(PI_D / 1023.0), &s, &c);
        wtc0 = c; wts0 = -s;
        m = (2045 * f) % 2046;
        __sincosf((float)m * (float)(PI_D / 1023.0), &s, &c);
        wtc1 = c; wts1 = -s;
    }

    const __hip_bfloat16* rowRe = Pt + (size_t)(2 * f) * PSTRIDE;
    const __hip_bfloat16* rowIm = rowRe + PSTRIDE;

    float acc = 0.f;
    const int tt0 = ty * 256 + 4 * lane;
    if (tt0 < NFRAMES) {
        short8 re0 = *(const short8*)(rowRe + 2 * tt0);
        short8 re1 = *(const short8*)(rowRe + 2 * tt0 + 8);
        short8 im0 = *(const short8*)(rowIm + 2 * tt0);
        short8 im1 = *(const short8*)(rowIm + 2 * tt0 + 8);
        float4 sT[4];
#pragma unroll
        for (int d = 0; d < 4; d++) sT[d] = S[tt0 + 4 + d];   // contiguous across wave
        float vr[16], vi[16];
#pragma unroll
        for (int j = 0; j < 8; j++) {
            vr[j] = b2f(re0[j]); vr[j + 8] = b2f(re1[j]);
            vi[j] = b2f(im0[j]); vi[j + 8] = b2f(im1[j]);
        }
#pragma unroll
        for (int d = 0; d < 4; d++) {
            const int tt = tt0 + d;
            if (tt >= NFRAMES) break;
            float xr = 0.f, xi = 0.f, yr = 0.f, yi = 0.f;
#pragma unroll
            for (int h = 0; h < 4; h++) {
                const int qx = 2 * d + 2 * h;
                xr += wc[h] * vr[qx] - ws[h] * vi[qx];
                xi += wc[h] * vi[qx] + ws[h] * vr[qx];
                const int qy = qx + 1;
                yr += wc[h] * vr[qy] - ws[h] * vi[qy];
                yi += wc[h] * vi[qy] + ws[h] * vr[qy];
            }
            const float4 sd = sT[d];
            xr += wtc0 * sd.x + wtc1 * sd.y;
            xi += wts0 * sd.x + wts1 * sd.y;
            yr += wtc0 * sd.z + wtc1 * sd.w;
            yi += wts0 * sd.z + wts1 * sd.w;
            float dm = sqrtf(xr * xr + xi * xi) - sqrtf(yr * yr + yi * yi);
            acc += dm * dm;
        }
    }
    acc = xorall(acc);
    if (lane == 0) atomicAdd(&mse_sum[f], acc);
}

// ---------------- invw body: invW[f] += sum_{b in 16-group, kk} |den|/|num| --------
__device__ __forceinline__ void invw_body(int bid, int tid,
                                          const float* __restrict__ ar,
                                          float* __restrict__ invW) {
    __shared__ float sar[16][12];
    const int f = (bid & 3) * 256 + tid;
    const int b0 = (bid >> 2) * 16;
    if (tid < 16 * 12) ((float*)sar)[tid] = ar[(size_t)b0 * 12 + tid];
    __syncthreads();

    const float omega = (float)(PI_D / 1024.0) * (float)f;
    float sw, cw;
    __sincosf(omega, &sw, &cw);

    float acc = 0.f;
#pragma unroll 4
    for (int bb = 0; bb < 16; bb++) {
        float a0 = sar[bb][0];
        float nr = a0, ni = 0.f, dr = a0, di = 0.f;
        float er = 1.f, ei = 0.f;
        float g1p = 1.f, g2p = 1.f;
#pragma unroll
        for (int j = 1; j < 12; j++) {
            float er2 = er * cw + ei * sw;
            float ei2 = ei * cw - er * sw;
            er = er2; ei = ei2;
            g1p *= 0.92f; g2p *= 0.6f;
            float aj = sar[bb][j];
            float a1 = aj * g1p, a2 = aj * g2p;
            nr += a2 * er; ni += a2 * ei;
            dr += a1 * er; di += a1 * ei;
            float D = dr * dr + di * di;
            float Nn = nr * nr + ni * ni;
            acc += D * __builtin_amdgcn_rsqf(D * Nn);
        }
    }
    atomicAdd(&invW[f], acc);
}

// ---------------- fused invW (FIRST, long-latency) + combine dispatch ----------------
__global__ __launch_bounds__(256) void combine_invw_kernel(
    const __hip_bfloat16* __restrict__ Pt,
    const float4* __restrict__ S,
    float* __restrict__ mse_sum,
    const float* __restrict__ ar,
    float* __restrict__ invW) {
    const int bid = blockIdx.x;
    const int tid = threadIdx.x;
    if (bid < INVW_BLOCKS) {
        invw_body(bid, tid, ar, invW);
    } else {
        const int cb = bid - INVW_BLOCKS;
        combine_body(cb & 255, cb >> 8, tid, Pt, S, mse_sum);
    }
}

// ---------------- final: out = sum_f mse_sum[f]*invW[f] / (4105*22528*1024) ----------------
__global__ void final_kernel(const float* __restrict__ mse_sum,
                             const float* __restrict__ invW,
                             float* __restrict__ out) {
    __shared__ float red[4];
    const int tid = threadIdx.x;
    float lo = 0.f;
    for (int f = tid; f < 1024; f += 256) lo += mse_sum[f] * invW[f];
    lo = wave_reduce(lo);
    if ((tid & 63) == 0) red[tid >> 6] = lo;
    __syncthreads();
    if (tid == 0) {
        float tot = red[0] + red[1] + red[2] + red[3];
        out[0] = tot * (float)(1.0 / (4105.0 * 22528.0 * 1024.0));
    }
}

extern "C" void kernel_launch(void* const* d_in, const int* in_sizes, int n_in,
                              void* d_out, int out_size, void* d_ws, size_t ws_size,
                              hipStream_t stream) {
    const float* x = (const float*)d_in[0];
    const float* y = (const float*)d_in[1];
    float* out = (float*)d_out;

    float* wsf = (float*)d_ws;
    float* mse_sum = wsf;                    // [0,1024) floats
    float* invW = wsf + 1024;                // [1024,2048)
    float* ar = wsf + 2080;                  // 2048*12 floats -> ends byte 106624
    float4* S = (float4*)((char*)d_ws + 131072);                     // 4352*16 = 69,632 B
    char* Ap = (char*)d_ws + 262144;                                 // 520*8192 = 4,259,840 B fp8
    char* Bp = (char*)d_ws + 4521984;                                // 128*8192 = 1,048,576 B fp8
    __hip_bfloat16* Pt = (__hip_bfloat16*)((char*)d_ws + 8388608);   // 2048*8224*2 = 33,685,504 B

    prep_kernel<<<PREP_BLOCKS, 256, 0, stream>>>(x, y, Ap, Bp, S, ar, wsf);
    gemm_p_kernel<<<dim3(NDIM / 128, MPAD / 128), 512, 0, stream>>>(Ap, Bp, Pt);
    combine_invw_kernel<<<INVW_BLOCKS + COMBINE_BLOCKS, 256, 0, stream>>>(Pt, S, mse_sum, ar, invW);
    final_kernel<<<1, 256, 0, stream>>>(mse_sum, invW, out);
}

// Round 16
// 119.249 us; speedup vs baseline: 1.1156x; 1.0514x over previous
//
#include <hip/hip_runtime.h>
#include <hip/hip_bf16.h>
#include <hip/hip_fp8.h>

#define PI_D 3.14159265358979323846
#define L_TOTAL 2097152
#define NFRAMES 4105      // 1 + L/511
#define NBLK    4108
#define MROWS_P 8216
#define KP      512       // 511 padded
#define NDIM    2048      // 1024 bins * (Re,Im)

// fp8 (OCP e4m3) permuted global layout for Ap and Bp, in 8B units of 8 fp8:
//   unit8(row, kc) = (row>>4)*1024 + kc*16 + (row&15),  kc = k/8 in [0,64)
// GEMM staging: linear 512B-per-wave copy; LDS fragment = rowblk*512 + lane*8.

// Fused GEMM+combine: M-tiles step 56 hop-blocks (112 rows, 16-aligned) so each
// frame's 4 hop-blocks live in one tile; C-tile goes to LDS (bf16), combine
// reads it there. Pt global buffer eliminated.
#define MTILES 74             // ceil(4105/56)
#define NTILES 16
#define INVW_BLOCKS 256       // 512-thread invw blocks (f half x 128 b-groups)
#define GC_BLOCKS (MTILES * NTILES)

// prep branch order: LONGEST-latency bodies first
#define BURG_BLOCKS   512
#define FRAMES_BLOCKS 1040   // 4160 waves, one per hop-block
#define BASIS_BLOCKS  256    // 1024 waves, one per frequency f
#define SARR_BLOCKS   17     // 4352 S entries (also zeroes accumulators)
#define PREP_BLOCKS   (BURG_BLOCKS + FRAMES_BLOCKS + BASIS_BLOCKS + SARR_BLOCKS)

typedef __attribute__((ext_vector_type(8))) short short8;
typedef __attribute__((ext_vector_type(4))) float floatx4;
typedef float floatx4u __attribute__((ext_vector_type(4), aligned(4)));

typedef __attribute__((address_space(1))) void gvoid_as1;
typedef __attribute__((address_space(3))) void lvoid_as3;

__device__ __forceinline__ void gld_lds16(const void* g, void* l) {
    __builtin_amdgcn_global_load_lds((gvoid_as1*)g, (lvoid_as3*)l, 16, 0, 0);
}

__device__ __forceinline__ unsigned int pk4_e4m3(float a, float b, float c, float d) {
    __hip_fp8_e4m3 q0(a), q1(b), q2(c), q3(d);
    return (unsigned int)q0.__x | ((unsigned int)q1.__x << 8)
         | ((unsigned int)q2.__x << 16) | ((unsigned int)q3.__x << 24);
}

__device__ __forceinline__ float xorall(float v) {
    v += __shfl_xor(v, 1, 64);
    v += __shfl_xor(v, 2, 64);
    v += __shfl_xor(v, 4, 64);
    v += __shfl_xor(v, 8, 64);
    v += __shfl_xor(v, 16, 64);
    v += __shfl_xor(v, 32, 64);
    return v;
}

__device__ __forceinline__ float wave_reduce(float v) {
    v += __shfl_down(v, 32, 64);
    v += __shfl_down(v, 16, 64);
    v += __shfl_down(v, 8, 64);
    v += __shfl_down(v, 4, 64);
    v += __shfl_down(v, 2, 64);
    v += __shfl_down(v, 1, 64);
    return v;
}

// ---------------- frames branch: build Ap (fp8 e4m3, permuted layout) --------------
__device__ __forceinline__ void frames_body(int bid, int tid,
                                            const float* __restrict__ x,
                                            const float* __restrict__ y,
                                            char* __restrict__ A) {
    const int lane = tid & 63;
    const int b = bid * 4 + (tid >> 6);          // 0..4159
    const int p0 = b * 511 + lane * 8 - 1023;
    float xv[8], yv[8];
    if (p0 >= 0 && p0 + 8 <= L_TOTAL) {
        floatx4u x0 = *(const floatx4u*)(x + p0);
        floatx4u x1 = *(const floatx4u*)(x + p0 + 4);
        floatx4u y0 = *(const floatx4u*)(y + p0);
        floatx4u y1 = *(const floatx4u*)(y + p0 + 4);
#pragma unroll
        for (int e = 0; e < 4; e++) { xv[e] = x0[e]; xv[4 + e] = x1[e]; }
#pragma unroll
        for (int e = 0; e < 4; e++) { yv[e] = y0[e]; yv[4 + e] = y1[e]; }
    } else {
#pragma unroll
        for (int e = 0; e < 8; e++) {
            int p = p0 + e;
            if (p < 0) p = -p;
            else if (p >= L_TOTAL) p = 2 * L_TOTAL - 2 - p;
            xv[e] = x[p];
            yv[e] = y[p];
        }
    }
    int4 pk;
    pk.x = (int)pk4_e4m3(xv[0], xv[1], xv[2], xv[3]);
    pk.y = (int)pk4_e4m3(xv[4], xv[5], xv[6], xv[7]);
    pk.z = (int)pk4_e4m3(yv[0], yv[1], yv[2], yv[3]);
    pk.w = (int)pk4_e4m3(yv[4], yv[5], yv[6], yv[7]);
    *(int4*)(A + (size_t)(b >> 3) * 8192 + lane * 128 + (b & 7) * 16) = pk;
}

// ---------------- basis branch: Bp (fp8 e4m3, permuted layout) ---------------------
__device__ __forceinline__ void basis_body(int bid, int tid,
                                           char* __restrict__ Bt) {
    const int lane = tid & 63;
    const int f = bid * 4 + (tid >> 6);          // 0..1023
    const int n0 = lane * 8;
    const int m0 = (f * n0) % 2046;
    float s, c, ss, cs;
    __sincosf((float)m0 * (float)(PI_D / 1023.0), &s, &c);
    __sincosf((float)f * (float)(PI_D / 1023.0), &ss, &cs);
    float cv[8], sv[8];
#pragma unroll
    for (int e = 0; e < 8; e++) {
        const int n = n0 + e;
        const bool valid = n < 511;
        cv[e] = valid ? c : 0.f;
        sv[e] = valid ? -s : 0.f;
        float c2 = c * cs - s * ss;
        float s2 = s * cs + c * ss;
        c = c2; s = s2;
    }
    int4 pk;
    pk.x = (int)pk4_e4m3(cv[0], cv[1], cv[2], cv[3]);
    pk.y = (int)pk4_e4m3(cv[4], cv[5], cv[6], cv[7]);
    pk.z = (int)pk4_e4m3(sv[0], sv[1], sv[2], sv[3]);
    pk.w = (int)pk4_e4m3(sv[4], sv[5], sv[6], sv[7]);
    *(int4*)(Bt + (size_t)(f >> 3) * 8192 + lane * 128 + (f & 7) * 16) = pk;
}

// ---------------- S branch: tail-sample table + accumulator zeroing ----------------
__device__ __forceinline__ void sarr_body(int bid, int tid,
                                          const float* __restrict__ x,
                                          const float* __restrict__ y,
                                          float4* __restrict__ S,
                                          float* __restrict__ wsf) {
    if (bid < 8) wsf[bid * 256 + tid] = 0.f;   // zero mse_sum + invW
    const int b = bid * 256 + tid;          // 0..4351
    int p0 = 511 * b - 1023;
    int p1 = p0 + 1;
    int m0 = (p0 < 0) ? -p0 : ((p0 >= L_TOTAL) ? 2 * L_TOTAL - 2 - p0 : p0);
    int m1 = (p1 < 0) ? -p1 : ((p1 >= L_TOTAL) ? 2 * L_TOTAL - 2 - p1 : p1);
    S[b] = make_float4(x[m0], x[m1], y[m0], y[m1]);
}

// ---------------- burg branch: one WAVE per 1024-sample audio block ----------------
__device__ __forceinline__ void burg_body(int bid, int tid,
                                          const float* __restrict__ y,
                                          float* __restrict__ ar_out) {
    const int lane = tid & 63;
    const int wid = tid >> 6;
    const int blk = bid * 4 + wid;
    const float4* yb4 = (const float4*)(y + (size_t)blk * 1024) + lane * 4;

    float t[16];
#pragma unroll
    for (int q = 0; q < 4; q++) {
        float4 v = yb4[q];
        t[q * 4 + 0] = v.x; t[q * 4 + 1] = v.y;
        t[q * 4 + 2] = v.z; t[q * 4 + 3] = v.w;
    }
    float b[16], f[16];
#pragma unroll
    for (int r = 0; r < 16; r++) b[r] = t[r];
#pragma unroll
    for (int r = 0; r < 15; r++) f[r] = t[r + 1];
    {
        float nb = __shfl_down(t[0], 1, 64);
        f[15] = (lane == 63) ? 0.f : nb;
        if (lane == 63) b[15] = 0.f;
    }

    float den = 0.f;
#pragma unroll
    for (int r = 0; r < 16; r++) den += f[r] * f[r] + b[r] * b[r];
    den = xorall(den);

    float ar_s[13];
    ar_s[0] = 1.f;
#pragma unroll
    for (int j = 1; j < 13; j++) ar_s[j] = 0.f;

#pragma unroll
    for (int i = 0; i < 12; i++) {
        float num = 0.f;
#pragma unroll
        for (int r = 0; r < 16; r++) num += f[r] * b[r];
        num = xorall(num);
        const float k = -2.f * num / den;

        float fu[16], bu[16];
#pragma unroll
        for (int r = 0; r < 16; r++) {
            fu[r] = f[r] + k * b[r];
            bu[r] = b[r] + k * f[r];
        }
        const float f0 = __shfl(fu[0], 0, 64);
        const int pos = 1022 - i;
        const int L = pos >> 4, S = pos & 15;
        const float blast = __shfl(bu[S], L, 64);

        den = (1.f - k * k) * den - blast * blast - f0 * f0;

        float nf = __shfl_down(fu[0], 1, 64);
#pragma unroll
        for (int r = 0; r < 15; r++) f[r] = fu[r + 1];
        f[15] = (lane == 63) ? 0.f : nf;
#pragma unroll
        for (int r = 0; r < 16; r++) b[r] = bu[r];
        if (lane == L) b[S] = 0.f;

        float tmp[13];
#pragma unroll
        for (int js = 1; js <= i + 1; js++) tmp[js] = ar_s[js] + k * ar_s[i + 1 - js];
#pragma unroll
        for (int js = 1; js <= i + 1; js++) ar_s[js] = tmp[js];
    }

#pragma unroll
    for (int j = 0; j < 12; j++)
        if (lane == j) ar_out[(size_t)blk * 12 + j] = ar_s[j];
}

// ---------------- fused prep ----------------
__global__ __launch_bounds__(256) void prep_kernel(const float* __restrict__ x,
                                                   const float* __restrict__ y,
                                                   char* __restrict__ A,
                                                   char* __restrict__ Bt,
                                                   float4* __restrict__ S,
                                                   float* __restrict__ ar,
                                                   float* __restrict__ wsf) {
    const int bid = blockIdx.x;
    const int tid = threadIdx.x;
    if (bid < BURG_BLOCKS) {
        burg_body(bid, tid, y, ar);
    } else if (bid < BURG_BLOCKS + FRAMES_BLOCKS) {
        frames_body(bid - BURG_BLOCKS, tid, x, y, A);
    } else if (bid < BURG_BLOCKS + FRAMES_BLOCKS + BASIS_BLOCKS) {
        basis_body(bid - BURG_BLOCKS - FRAMES_BLOCKS, tid, Bt);
    } else {
        sarr_body(bid - BURG_BLOCKS - FRAMES_BLOCKS - BASIS_BLOCKS, tid, x, y, S, wsf);
    }
}

// ---------------- invw body (512-thread): invW[f] += sum over 16 b's ---------------
__device__ __forceinline__ void invw_body(int bid, int tid, char* smem,
                                          const float* __restrict__ ar,
                                          float* __restrict__ invW) {
    float (*sar)[12] = (float(*)[12])smem;
    const int f = (bid & 1) * 512 + tid;     // 0..1023
    const int b0 = (bid >> 1) * 16;
    if (tid < 16 * 12) ((float*)sar)[tid] = ar[(size_t)b0 * 12 + tid];
    __syncthreads();

    const float omega = (float)(PI_D / 1024.0) * (float)f;
    float sw, cw;
    __sincosf(omega, &sw, &cw);

    float acc = 0.f;
#pragma unroll 4
    for (int bb = 0; bb < 16; bb++) {
        float a0 = sar[bb][0];
        float nr = a0, ni = 0.f, dr = a0, di = 0.f;
        float er = 1.f, ei = 0.f;
        float g1p = 1.f, g2p = 1.f;
#pragma unroll
        for (int j = 1; j < 12; j++) {
            float er2 = er * cw + ei * sw;
            float ei2 = ei * cw - er * sw;
            er = er2; ei = ei2;
            g1p *= 0.92f; g2p *= 0.6f;
            float aj = sar[bb][j];
            float a1 = aj * g1p, a2 = aj * g2p;
            nr += a2 * er; ni += a2 * ei;
            dr += a1 * er; di += a1 * ei;
            float D = dr * dr + di * di;
            float Nn = nr * nr + ni * ni;
            acc += D * __builtin_amdgcn_rsqf(D * Nn);
        }
    }
    atomicAdd(&invW[f], acc);
}

// ---------------- fused GEMM + combine body (no Pt) --------------------------------
// Tile: cols [128bx, +128) = 64 f's; hop-blocks [56by, 56by+64); frames [56by, +56).
// After K-loop, C goes to LDS bf16 [row][col]; combine reads it in-block.
__device__ __forceinline__ void gemm_combine_body(
    int bx, int by, int tid, char* smem,
    const char* __restrict__ A, const char* __restrict__ Bt,
    const float4* __restrict__ S, float* __restrict__ mse_sum) {
    char* stg = smem;                                   // 8 KB staging
    unsigned short* Cl = (unsigned short*)(smem + 8192); // 128x128 bf16 = 32 KB
    float* msePart = (float*)(smem + 8192 + 32768);      // 64 floats

    const int tid9 = tid;
    const int lane = tid9 & 63;
    const int w = tid9 >> 6;
    const int wm = w >> 1, wn = w & 1;
    const int q = lane >> 4, l15 = lane & 15;
    const int tileN = bx * 128;
    const int tileMblk = by * 56;            // hop-block base
    const int tileM = tileMblk * 2;          // row base (multiple of 16: 112*by)

    if (tid9 < 64) msePart[tid9] = 0.f;

    floatx4 acc[2][4];
#pragma unroll
    for (int i = 0; i < 2; i++)
#pragma unroll
        for (int j = 0; j < 4; j++) acc[i][j] = (floatx4){0.f, 0.f, 0.f, 0.f};

    const int t8 = tid9 & 255;
    const int g = t8 >> 5;
    const int u = t8 & 31;
    const char* p = ((tid9 < 256)
        ? A + (((size_t)(tileM >> 4) + g) << 13)
        : Bt + (((size_t)(tileN >> 4) + g) << 13)) + u * 16;

    for (int it = 0; it < KP / 32; it++) {
        gld_lds16(p, stg + tid9 * 16);
        p += 512;
        __syncthreads();

        long af[2], bf[4];
#pragma unroll
        for (int sm = 0; sm < 2; sm++)
            af[sm] = *(const long*)(stg + (wm * 2 + sm) * 512 + lane * 8);
#pragma unroll
        for (int sn = 0; sn < 4; sn++)
            bf[sn] = *(const long*)(stg + 4096 + (wn * 4 + sn) * 512 + lane * 8);
#pragma unroll
        for (int sm = 0; sm < 2; sm++)
#pragma unroll
            for (int sn = 0; sn < 4; sn++)
                acc[sm][sn] = __builtin_amdgcn_mfma_f32_16x16x32_fp8_fp8(
                    af[sm], bf[sn], acc[sm][sn], 0, 0, 0);
        __syncthreads();
    }

    // C -> LDS bf16 [row][col]; C/D layout: col=lane&15 (N), row=quad*4+reg (M)
#pragma unroll
    for (int sm = 0; sm < 2; sm++) {
        const int rowB = wm * 32 + sm * 16 + q * 4;
#pragma unroll
        for (int sn = 0; sn < 4; sn++) {
            const int col = wn * 64 + sn * 16 + l15;
#pragma unroll
            for (int r = 0; r < 4; r++) {
                __hip_bfloat16 h = __float2bfloat16(acc[sm][sn][r]);
                Cl[(rowB + r) * 128 + col] = *(unsigned short*)&h;
            }
        }
    }
    __syncthreads();

    // combine: lane -> f_local; wave -> 7-frame group
    const int fg = (tileN >> 1) + lane;      // global f 0..1023
    float wc[4], ws[4];
    wc[0] = 1.f; ws[0] = 0.f;
#pragma unroll
    for (int h = 1; h < 4; h++) {
        int m = (511 * h * fg) % 2046;
        float s, c;
        __sincosf((float)m * (float)(PI_D / 1023.0), &s, &c);
        wc[h] = c; ws[h] = -s;
    }
    float wtc0, wts0, wtc1, wts1;
    {
        int m = (2044 * fg) % 2046;
        float s, c;
        __sincosf((float)m * (float)(PI_D / 1023.0), &s, &c);
        wtc0 = c; wts0 = -s;
        m = (2045 * fg) % 2046;
        __sincosf((float)m * (float)(PI_D / 1023.0), &s, &c);
        wtc1 = c; wts1 = -s;
    }

    const unsigned int* Cd = (const unsigned int*)Cl;   // dword idx = row*64 + lane
    float accm = 0.f;
#pragma unroll
    for (int d = 0; d < 7; d++) {
        const int tl = w * 7 + d;            // local frame 0..55
        const int tg = tileMblk + tl;        // global frame
        if (tg >= NFRAMES) break;            // wave-uniform
        float xr = 0.f, xi = 0.f, yr = 0.f, yi = 0.f;
#pragma unroll
        for (int h = 0; h < 4; h++) {
            const int bl = tl + h;           // local hop-block 0..62
            unsigned int ux = Cd[(2 * bl) * 64 + lane];       // x-row: (Re lo, Im hi)
            unsigned int uy = Cd[(2 * bl + 1) * 64 + lane];   // y-row
            float vrx = __uint_as_float(ux << 16);
            float vix = __uint_as_float(ux & 0xFFFF0000u);
            float vry = __uint_as_float(uy << 16);
            float viy = __uint_as_float(uy & 0xFFFF0000u);
            xr += wc[h] * vrx - ws[h] * vix;
            xi += wc[h] * vix + ws[h] * vrx;
            yr += wc[h] * vry - ws[h] * viy;
            yi += wc[h] * viy + ws[h] * vry;
        }
        const float4 sd = S[tg + 4];         // tail samples (broadcast per wave)
        xr += wtc0 * sd.x + wtc1 * sd.y;
        xi += wts0 * sd.x + wts1 * sd.y;
        yr += wtc0 * sd.z + wtc1 * sd.w;
        yi += wts0 * sd.z + wts1 * sd.w;
        float dm = sqrtf(xr * xr + xi * xi) - sqrtf(yr * yr + yi * yi);
        accm += dm * dm;
    }
    atomicAdd(&msePart[lane], accm);
    __syncthreads();
    if (tid9 < 64) atomicAdd(&mse_sum[(tileN >> 1) + tid9], msePart[tid9]);
}

// ---------------- fused invw (FIRST) + gemm_combine dispatch ----------------------
__global__ __launch_bounds__(512, 4) void gemm_combine_kernel(
    const char* __restrict__ A, const char* __restrict__ Bt,
    const float4* __restrict__ S, float* __restrict__ mse_sum,
    const float* __restrict__ ar, float* __restrict__ invW) {
    __shared__ __align__(16) char smem[8192 + 32768 + 256];
    const int bid = blockIdx.x;
    const int tid = threadIdx.x;
    if (bid < INVW_BLOCKS) {
        invw_body(bid, tid, smem, ar, invW);
    } else {
        const int b = bid - INVW_BLOCKS;
        gemm_combine_body(b & 15, b >> 4, tid, smem, A, Bt, S, mse_sum);
    }
}

// ---------------- final: out = sum_f mse_sum[f]*invW[f] / (4105*22528*1024) --------
__global__ void final_kernel(const float* __restrict__ mse_sum,
                             const float* __restrict__ invW,
                             float* __restrict__ out) {
    __shared__ float red[4];
    const int tid = threadIdx.x;
    float lo = 0.f;
    for (int f = tid; f < 1024; f += 256) lo += mse_sum[f] * invW[f];
    lo = wave_reduce(lo);
    if ((tid & 63) == 0) red[tid >> 6] = lo;
    __syncthreads();
    if (tid == 0) {
        float tot = red[0] + red[1] + red[2] + red[3];
        out[0] = tot * (float)(1.0 / (4105.0 * 22528.0 * 1024.0));
    }
}

extern "C" void kernel_launch(void* const* d_in, const int* in_sizes, int n_in,
                              void* d_out, int out_size, void* d_ws, size_t ws_size,
                              hipStream_t stream) {
    const float* x = (const float*)d_in[0];
    const float* y = (const float*)d_in[1];
    float* out = (float*)d_out;

    float* wsf = (float*)d_ws;
    float* mse_sum = wsf;                    // [0,1024) floats
    float* invW = wsf + 1024;                // [1024,2048)
    float* ar = wsf + 2080;                  // 2048*12 floats
    float4* S = (float4*)((char*)d_ws + 131072);     // 4352*16 = 69,632 B
    char* Ap = (char*)d_ws + 262144;                 // 520*8192 = 4,259,840 B fp8
    char* Bp = (char*)d_ws + 4521984;                // 128*8192 = 1,048,576 B fp8

    prep_kernel<<<PREP_BLOCKS, 256, 0, stream>>>(x, y, Ap, Bp, S, ar, wsf);
    gemm_combine_kernel<<<INVW_BLOCKS + GC_BLOCKS, 512, 0, stream>>>(Ap, Bp, S, mse_sum, ar, invW);
    final_kernel<<<1, 256, 0, stream>>>(mse_sum, invW, out);
}